// Round 3
// baseline (56.043 us; speedup 1.0000x reference)
//
#include <hip/hip_runtime.h>

// Sinusoidal oscillator with FM: out[b,n] = sin(2*pi * exclusive_cumsum_n(f0_rev*(1+mod_env*amt)))
// Phase scan in f64 (revolutions); hardware v_sin_f32 (input in revolutions).
// R3: non-temporal output stores via native ext_vector type (fixes R2 compile),
//     single barrier per chunk via double-buffered wave sums + redundant cross-wave scan.

constexpr int BLOCK = 1024;   // threads per block (one block per row)
constexpr int VPT   = 8;      // values per thread per chunk
constexpr int NW    = BLOCK / 64;  // 16 waves

typedef float f32x4 __attribute__((ext_vector_type(4)));

__global__ __launch_bounds__(BLOCK) void osc_kernel(
    const float* __restrict__ freq,        // [B]
    const float* __restrict__ mod_env,     // [B, N]
    const float* __restrict__ mod_amount,  // [B]
    float* __restrict__ out,               // [B, N]
    int N)
{
    const int row  = blockIdx.x;
    const int tid  = threadIdx.x;
    const int lane = tid & 63;
    const int wid  = tid >> 6;

    __shared__ double s_wsum[2][NW];      // double-buffered per-wave chunk sums

    // Per-row constants (f64)
    const double f0rev = (20.0 + 1980.0 * (double)freq[row]) / 48000.0;  // rev/sample
    const double amt   = -1.0 + 3.0 * (double)mod_amount[row];
    const double k     = f0rev * amt;     // freq_env_rev = f0rev + me * k

    const float* __restrict__ rowp = mod_env + (size_t)row * N;
    float* __restrict__ outp       = out     + (size_t)row * N;

    const int chunk  = BLOCK * VPT;       // 8192
    const int nchunk = N / chunk;         // 8

    double carry = 0.0;

    // Prefetch chunk 0
    const float* p0 = rowp + tid * VPT;
    f32x4 curA = *(const f32x4*)(p0);
    f32x4 curB = *(const f32x4*)(p0 + 4);

    for (int c = 0; c < nchunk; ++c) {
        // Prefetch next chunk while computing this one
        f32x4 nxtA = curA, nxtB = curB;
        if (c + 1 < nchunk) {
            const float* p = rowp + (size_t)(c + 1) * chunk + tid * VPT;
            nxtA = *(const f32x4*)(p);
            nxtB = *(const f32x4*)(p + 4);
        }

        // Per-element increments (rev/sample), f64
        double v0 = fma((double)curA.x, k, f0rev);
        double v1 = fma((double)curA.y, k, f0rev);
        double v2 = fma((double)curA.z, k, f0rev);
        double v3 = fma((double)curA.w, k, f0rev);
        double v4 = fma((double)curB.x, k, f0rev);
        double v5 = fma((double)curB.y, k, f0rev);
        double v6 = fma((double)curB.z, k, f0rev);
        double v7 = fma((double)curB.w, k, f0rev);

        double tsum = ((v0 + v1) + (v2 + v3)) + ((v4 + v5) + (v6 + v7));

        // Wave-level inclusive scan of per-thread sums
        double x = tsum;
        #pragma unroll
        for (int off = 1; off < 64; off <<= 1) {
            double y = __shfl_up(x, off, 64);
            if (lane >= off) x += y;
        }

        if (lane == 63) s_wsum[c & 1][wid] = x;
        __syncthreads();   // the only barrier this chunk

        // Every wave redundantly scans the 16 wave sums (no second sync needed)
        double w = (lane < NW) ? s_wsum[c & 1][lane] : 0.0;
        #pragma unroll
        for (int off = 1; off < NW; off <<= 1) {
            double y = __shfl_up(w, off, 64);
            if (lane >= off) w += y;
        }
        double total = __shfl(w, NW - 1, 64);
        double exc   = __shfl(w, (wid > 0 ? wid - 1 : 0), 64);
        if (wid == 0) exc = 0.0;

        // Exclusive phase base for this thread (revolutions)
        double phase = carry + exc + (x - tsum);
        carry += total;

        f32x4 oA, oB;
        {
            double pf;
            pf = phase - floor(phase); oA.x = __builtin_amdgcn_sinf((float)pf); phase += v0;
            pf = phase - floor(phase); oA.y = __builtin_amdgcn_sinf((float)pf); phase += v1;
            pf = phase - floor(phase); oA.z = __builtin_amdgcn_sinf((float)pf); phase += v2;
            pf = phase - floor(phase); oA.w = __builtin_amdgcn_sinf((float)pf); phase += v3;
            pf = phase - floor(phase); oB.x = __builtin_amdgcn_sinf((float)pf); phase += v4;
            pf = phase - floor(phase); oB.y = __builtin_amdgcn_sinf((float)pf); phase += v5;
            pf = phase - floor(phase); oB.z = __builtin_amdgcn_sinf((float)pf); phase += v6;
            pf = phase - floor(phase); oB.w = __builtin_amdgcn_sinf((float)pf); phase += v7;
        }

        // Non-temporal stores: output is write-once, keep input resident in LLC
        float* q = outp + (size_t)c * chunk + tid * VPT;
        __builtin_nontemporal_store(oA, (f32x4*)(q));
        __builtin_nontemporal_store(oB, (f32x4*)(q + 4));

        curA = nxtA; curB = nxtB;
    }
}

extern "C" void kernel_launch(void* const* d_in, const int* in_sizes, int n_in,
                              void* d_out, int out_size, void* d_ws, size_t ws_size,
                              hipStream_t stream) {
    const float* freq       = (const float*)d_in[1];
    const float* mod_env    = (const float*)d_in[2];
    const float* mod_amount = (const float*)d_in[3];
    float* out = (float*)d_out;

    const int B = in_sizes[1];              // 512
    const int N = in_sizes[2] / B;          // 65536

    osc_kernel<<<B, BLOCK, 0, stream>>>(freq, mod_env, mod_amount, out, N);
}